// Round 6
// baseline (431.364 us; speedup 1.0000x reference)
//
#include <hip/hip_runtime.h>
#include <math.h>

// Problem constants (B=2, S=2048, D=1024, H=16, hd=64, K=16)
#define SEQ 2048
#define DIM 1024
#define NB  2
#define NH  16

typedef __attribute__((ext_vector_type(8))) short short8;
typedef __attribute__((ext_vector_type(4))) float floatx4;

__device__ __forceinline__ ushort f2bf(float f) {
    unsigned u = __float_as_uint(f);
    return (ushort)((u + 0x7FFFu + ((u >> 16) & 1u)) >> 16);
}
__device__ __forceinline__ float bf2f(ushort h) {
    return __uint_as_float(((unsigned)h) << 16);
}
// async global->LDS, 16B per lane; LDS dest = wave-uniform base + lane*16
__device__ __forceinline__ void gload16(const void* g, char* lds_base) {
    __builtin_amdgcn_global_load_lds(
        (const __attribute__((address_space(1))) void*)g,
        (__attribute__((address_space(3))) void*)lds_base, 16, 0, 0);
}

// ---------------------------------------------------------------------------
// fp32 -> bf16
// ---------------------------------------------------------------------------
__global__ __launch_bounds__(256) void cvt_hi_kernel(
    const float* __restrict__ src, ushort* __restrict__ dst, int n)
{
    int i = (blockIdx.x * 256 + threadIdx.x) * 4;
    if (i >= n) return;
    float4 v = *(const float4*)(src + i);
    ushort4 o;
    o.x = f2bf(v.x); o.y = f2bf(v.y); o.z = f2bf(v.z); o.w = f2bf(v.w);
    *(ushort4*)(dst + i) = o;
}

// ---------------------------------------------------------------------------
// transpose + cvt: src [R][C] fp32 -> dst [C][R] bf16. grid (C/64, R/64).
// ---------------------------------------------------------------------------
__global__ __launch_bounds__(256) void txp_kernel(
    const float* __restrict__ src, ushort* __restrict__ dst, int R, int C)
{
    __shared__ ushort T[64 * 72];
    const int t = threadIdx.x;
    const int c0 = blockIdx.x * 64, r0 = blockIdx.y * 64;
    #pragma unroll
    for (int it = 0; it < 4; ++it) {
        int r = 16 * it + (t >> 4);
        int c4 = (t & 15) * 4;
        float4 v = *(const float4*)(src + (size_t)(r0 + r) * C + c0 + c4);
        T[(c4 + 0) * 72 + r] = f2bf(v.x);
        T[(c4 + 1) * 72 + r] = f2bf(v.y);
        T[(c4 + 2) * 72 + r] = f2bf(v.z);
        T[(c4 + 3) * 72 + r] = f2bf(v.w);
    }
    __syncthreads();
    {
        int c = t >> 2, rb = (t & 3) * 16;
        ushort tmp[16];
        #pragma unroll
        for (int i = 0; i < 16; ++i) tmp[i] = T[c * 72 + rb + i];
        ushort* d = dst + (size_t)(c0 + c) * R + r0 + rb;
        *(short8*)(d) = *(short8*)(tmp);
        *(short8*)(d + 8) = *(short8*)(tmp + 8);
    }
}

// ---------------------------------------------------------------------------
// K1: per-diff stats
// ---------------------------------------------------------------------------
__global__ __launch_bounds__(256) void traj_stats_kernel(
    const float* __restrict__ x, float* __restrict__ sbuf, float* __restrict__ invbuf)
{
    const int wave = threadIdx.x >> 6;
    const int lane = threadIdx.x & 63;
    const int row  = blockIdx.x * 4 + wave;
    const int NR = NB * (SEQ - 1);
    if (row >= NR) return;
    const int b = row / (SEQ - 1);
    const int j = row - b * (SEQ - 1);
    const float* x0 = x + ((size_t)(b * SEQ + j)) * DIM;
    const float* x1 = x0 + DIM;
    float sum = 0.f;
    #pragma unroll
    for (int q = 0; q < 4; ++q) {
        int idx = q * 256 + lane * 4;
        float4 a = *(const float4*)(x0 + idx);
        float4 c = *(const float4*)(x1 + idx);
        float dx = c.x-a.x, dy = c.y-a.y, dz = c.z-a.z, dw = c.w-a.w;
        sum += dx*dx + dy*dy + dz*dz + dw*dw;
    }
    #pragma unroll
    for (int off = 32; off > 0; off >>= 1) sum += __shfl_down(sum, off);
    if (lane == 0) {
        float mag = sqrtf(sum);
        sbuf[row]   = tanhf(mag);
        invbuf[row] = 1.0f / fmaxf(mag, 1e-8f);
    }
}

// ---------------------------------------------------------------------------
// K2: traj combine (window <= 8)
// ---------------------------------------------------------------------------
__global__ __launch_bounds__(256) void traj_kernel(
    const float* __restrict__ x, const float* __restrict__ sbuf,
    const float* __restrict__ invbuf, float* __restrict__ traj_out)
{
    const int bp = blockIdx.x;
    const int b  = bp >> 11;
    const int p  = bp & (SEQ - 1);
    int ws = p - 8; if (ws < 0) ws = 0;
    const int wlen = p - ws;
    const float wsz = (float)((p - ws) > 1 ? (p - ws) : 1);
    const int base = b * (SEQ - 1) + ws;

    float Z = 0.f;
    for (int t = 0; t < wlen; ++t)
        Z += sbuf[base + t] * ((float)(t + 1) / wsz);
    const float scale = 1.0f / fmaxf(Z, 1e-8f);

    const int d0 = threadIdx.x * 4;
    const float* xb = x + ((size_t)(b * SEQ + ws)) * DIM + d0;
    float4 prev = *(const float4*)xb;
    float4 acc = make_float4(0.f,0.f,0.f,0.f);
    for (int t = 0; t < wlen; ++t) {
        xb += DIM;
        float4 cur = *(const float4*)xb;
        float cc = sbuf[base + t] * ((float)(t + 1) / wsz) * invbuf[base + t] * scale;
        acc.x += cc * (cur.x - prev.x);
        acc.y += cc * (cur.y - prev.y);
        acc.z += cc * (cur.z - prev.z);
        acc.w += cc * (cur.w - prev.w);
        prev = cur;
    }
    *(float4*)(traj_out + (size_t)bp * DIM + d0) = acc;
}

// ---------------------------------------------------------------------------
// MFMA bf16 GEMM, m97 structure: C[M,N] = A[M,KTOT] @ B[N,KTOT]^T.
// 128x128 tile, BK=32, 4 waves 2x2, each wave 64x64 via 4x4 of 16x16x32.
// EPI=3 (q/k): bf16 head-major store: n<1024 -> qwb, else kwb.
// EPI=4: fp32 store to cout[(z*2048+gm)*1024+gn] (final K=288 gemm).
// ---------------------------------------------------------------------------
template<int KTOT, int EPI>
__global__ __launch_bounds__(256) void mm_kernel(
    const ushort* __restrict__ Ag, const ushort* __restrict__ Bg,
    float* __restrict__ cout, ushort* __restrict__ qwb, ushort* __restrict__ kwb,
    long aStride, long bStride)
{
    __shared__ char smem[16384];
    const int tid = threadIdx.x;
    const int l = tid & 63;
    const int w = tid >> 6;
    const int wm = w >> 1, wn = w & 1;
    const int n0 = blockIdx.x * 128;
    const int m0 = blockIdx.y * 128;
    const int zb = blockIdx.z;

    char* a_s = smem;
    char* b_s = smem + 8192;

    const int srow = 32 * w + (l >> 2);
    const int scol = (l & 3) * 8;
    const ushort* Ah = Ag + (size_t)zb * aStride + (size_t)(m0 + srow) * KTOT + scol;
    const ushort* Bh = Bg + (size_t)zb * bStride + (size_t)(n0 + srow) * KTOT + scol;

    floatx4 acc[4][4] = {};
    const int fr = l & 15;
    const int fq = (l >> 4) * 16;

    for (int kb = 0; kb < KTOT; kb += 32) {
        if (kb) __syncthreads();
        gload16(Ah + kb,            a_s + w*2048);
        gload16(Ah + kb + 16*KTOT,  a_s + w*2048 + 1024);
        gload16(Bh + kb,            b_s + w*2048);
        gload16(Bh + kb + 16*KTOT,  b_s + w*2048 + 1024);
        __syncthreads();
        short8 fa[4], fb[4];
        #pragma unroll
        for (int t = 0; t < 4; ++t) {
            fa[t] = *(const short8*)(a_s + ((wm*64 + t*16 + fr) << 6) + fq);
            fb[t] = *(const short8*)(b_s + ((wn*64 + t*16 + fr) << 6) + fq);
        }
        #pragma unroll
        for (int it = 0; it < 4; ++it)
            #pragma unroll
            for (int jt = 0; jt < 4; ++jt)
                acc[it][jt] = __builtin_amdgcn_mfma_f32_16x16x32_bf16(
                    fa[it], fb[jt], acc[it][jt], 0, 0, 0);
    }

    const int row0 = (l >> 4) * 4;   // C: row=(l>>4)*4+reg, col=l&15
    const int col  = l & 15;

    if (EPI == 3) {
        ushort* obuf = (n0 < 1024) ? qwb : kwb;
        const int nb = n0 & 1023;
        #pragma unroll
        for (int it = 0; it < 4; ++it)
            #pragma unroll
            for (int jt = 0; jt < 4; ++jt)
                #pragma unroll
                for (int r = 0; r < 4; ++r) {
                    int gm = m0 + wm*64 + it*16 + row0 + r;     // token
                    int gn = nb + wn*64 + jt*16 + col;          // h*64+d
                    int hh = gn >> 6, d = gn & 63;
                    int bb = gm >> 11, ss = gm & (SEQ - 1);
                    obuf[(((size_t)(bb*NH + hh))*SEQ + ss)*64 + d] = f2bf(acc[it][jt][r]);
                }
    } else {
        #pragma unroll
        for (int it = 0; it < 4; ++it)
            #pragma unroll
            for (int jt = 0; jt < 4; ++jt)
                #pragma unroll
                for (int r = 0; r < 4; ++r) {
                    int gm = m0 + wm*64 + it*16 + row0 + r;
                    int gn = n0 + wn*64 + jt*16 + col;
                    cout[((size_t)(zb*2048 + gm))*1024 + gn] = acc[it][jt][r];
                }
    }
}

// ---------------------------------------------------------------------------
// Splat weights (q side): fp32 out [bh][s][16]
// ---------------------------------------------------------------------------
__global__ __launch_bounds__(256) void splat_q_kernel(
    const ushort* __restrict__ qk, float* __restrict__ wout,
    const float* __restrict__ centers, const float* __restrict__ lscales,
    const float* __restrict__ amps)
{
    __shared__ float Cs[16*64];
    __shared__ float Pr[48];
    const int tid = threadIdx.x;
    const int bh  = blockIdx.x >> 3;
    const int h   = bh & 15;
    const int s   = (blockIdx.x & 7) * 256 + tid;
    *(float4*)(Cs + tid*4) = *(const float4*)(centers + (size_t)h*1024 + tid*4);
    if (tid < 16) {
        float s2 = __expf(2.f * lscales[h*16 + tid]);
        Pr[tid]      = -0.5f / s2;
        Pr[16 + tid] = 1.f / (1.f + __expf(-amps[h*16 + tid]));
        const float* cp = centers + ((size_t)h*16 + tid)*64;
        float cn = 0.f;
        for (int i = 0; i < 64; ++i) cn += cp[i]*cp[i];
        Pr[32 + tid] = cn;
    }
    __syncthreads();

    float q[64];
    const ushort* qp = qk + ((size_t)bh*SEQ + s)*64;
    #pragma unroll
    for (int i = 0; i < 8; ++i) {
        short8 v = *(const short8*)(qp + i*8);
        #pragma unroll
        for (int j = 0; j < 8; ++j) q[i*8+j] = bf2f((ushort)v[j]);
    }
    float tn = 0.f;
    #pragma unroll
    for (int i = 0; i < 64; ++i) tn = fmaf(q[i], q[i], tn);

    float o16[16];
    #pragma unroll 4
    for (int sp = 0; sp < 16; ++sp) {
        const float* cp = Cs + sp*64;
        float cr = 0.f;
        #pragma unroll
        for (int i = 0; i < 64; ++i) cr = fmaf(q[i], cp[i], cr);
        float dq = tn - 2.f*cr + Pr[32 + sp];
        o16[sp] = __expf(dq * Pr[sp]) * Pr[16 + sp];
    }
    float* op = wout + ((size_t)bh*SEQ + s)*16;
    #pragma unroll
    for (int i = 0; i < 4; ++i)
        *(float4*)(op + i*4) = *(float4*)(o16 + i*4);
}

// ---------------------------------------------------------------------------
// Splat weights (k side): transposed bf16 out kwA [bh][32 rows][2048]:
// rows 0..15 = kw^T, row 16 = ones (xSum trick), rows 17..31 unused.
// ---------------------------------------------------------------------------
__global__ __launch_bounds__(256) void splat_k_kernel(
    const ushort* __restrict__ qk, ushort* __restrict__ kwA,
    const float* __restrict__ centers, const float* __restrict__ lscales,
    const float* __restrict__ amps)
{
    __shared__ float Cs[16*64];
    __shared__ float Pr[48];
    __shared__ ushort Tr[16][264];
    const int tid = threadIdx.x;
    const int bh  = blockIdx.x >> 3;
    const int h   = bh & 15;
    const int s0  = (blockIdx.x & 7) * 256;
    const int s   = s0 + tid;
    *(float4*)(Cs + tid*4) = *(const float4*)(centers + (size_t)h*1024 + tid*4);
    if (tid < 16) {
        float s2 = __expf(2.f * lscales[h*16 + tid]);
        Pr[tid]      = -0.5f / s2;
        Pr[16 + tid] = 1.f / (1.f + __expf(-amps[h*16 + tid]));
        const float* cp = centers + ((size_t)h*16 + tid)*64;
        float cn = 0.f;
        for (int i = 0; i < 64; ++i) cn += cp[i]*cp[i];
        Pr[32 + tid] = cn;
    }
    __syncthreads();

    float q[64];
    const ushort* qp = qk + ((size_t)bh*SEQ + s)*64;
    #pragma unroll
    for (int i = 0; i < 8; ++i) {
        short8 v = *(const short8*)(qp + i*8);
        #pragma unroll
        for (int j = 0; j < 8; ++j) q[i*8+j] = bf2f((ushort)v[j]);
    }
    float tn = 0.f;
    #pragma unroll
    for (int i = 0; i < 64; ++i) tn = fmaf(q[i], q[i], tn);

    #pragma unroll 4
    for (int sp = 0; sp < 16; ++sp) {
        const float* cp = Cs + sp*64;
        float cr = 0.f;
        #pragma unroll
        for (int i = 0; i < 64; ++i) cr = fmaf(q[i], cp[i], cr);
        float dq = tn - 2.f*cr + Pr[32 + sp];
        Tr[sp][tid] = f2bf(__expf(dq * Pr[sp]) * Pr[16 + sp]);
    }
    __syncthreads();
    {
        int p = tid >> 4, seg = (tid & 15) * 16;
        ushort tmp[16];
        #pragma unroll
        for (int i = 0; i < 16; ++i) tmp[i] = Tr[p][seg + i];
        ushort* d = kwA + ((size_t)bh*32 + p)*2048 + s0 + seg;
        *(short8*)(d) = *(short8*)(tmp);
        *(short8*)(d + 8) = *(short8*)(tmp + 8);
    }
    kwA[((size_t)bh*32 + 16)*2048 + s] = 0x3F80;   // ones row
}

// ---------------------------------------------------------------------------
// kSum[bh][p] = sum_s kwA[bh][p][s]
// ---------------------------------------------------------------------------
__global__ __launch_bounds__(256) void ksum_kernel(
    const ushort* __restrict__ kwA, float* __restrict__ kSum)
{
    __shared__ float R[256];
    const int bh = blockIdx.x;
    const int t = threadIdx.x;
    const int p = t >> 4, seg = t & 15;
    const ushort* row = kwA + ((size_t)bh*32 + p)*2048 + seg*128;
    float s = 0.f;
    #pragma unroll
    for (int i = 0; i < 16; ++i) {
        short8 v = *(const short8*)(row + i*8);
        #pragma unroll
        for (int j = 0; j < 8; ++j) s += bf2f((ushort)v[j]);
    }
    R[t] = s;
    __syncthreads();
    if (t < 16) {
        float tot = 0.f;
        #pragma unroll
        for (int j = 0; j < 16; ++j) tot += R[t*16 + j];
        kSum[bh*16 + t] = tot;
    }
}

// ---------------------------------------------------------------------------
// T' [bh][17][1024] = kwA[bh] (32x2048) @ xT[b] (1024x2048)^T, rows<17 stored.
// grid (8 ntiles, 32 bh). tile 32m x 128n, BK=32.
// ---------------------------------------------------------------------------
__global__ __launch_bounds__(256) void tgemm_kernel(
    const ushort* __restrict__ kwA, const ushort* __restrict__ xT,
    float* __restrict__ Tbuf)
{
    __shared__ char smem[2048 + 8192];
    const int tid = threadIdx.x;
    const int l = tid & 63, w = tid >> 6;
    const int bh = blockIdx.y, b = bh >> 4;
    const int n0 = blockIdx.x * 128;
    const ushort* Ab = kwA + (size_t)bh * 32 * 2048;
    const ushort* Bb = xT + ((size_t)b * 1024 + n0) * 2048;
    char* a_s = smem;
    char* b_s = smem + 2048;
    const int lr = l >> 2, lc = (l & 3) * 8;
    floatx4 acc[2][2] = {};
    const int fr = l & 15, fq = (l >> 4) * 16;

    for (int kb = 0; kb < 2048; kb += 32) {
        if (kb) __syncthreads();
        if (w < 2)
            gload16(Ab + (size_t)(16*w + lr)*2048 + kb + lc, a_s + w*1024);
        gload16(Bb + (size_t)(32*w + lr)*2048 + kb + lc,      b_s + w*2048);
        gload16(Bb + (size_t)(32*w + 16 + lr)*2048 + kb + lc, b_s + w*2048 + 1024);
        __syncthreads();
        short8 fa[2], fb[2];
        #pragma unroll
        for (int i = 0; i < 2; ++i) {
            fa[i] = *(const short8*)(a_s + ((i*16 + fr) << 6) + fq);
            fb[i] = *(const short8*)(b_s + ((w*32 + i*16 + fr) << 6) + fq);
        }
        #pragma unroll
        for (int it = 0; it < 2; ++it)
            #pragma unroll
            for (int jt = 0; jt < 2; ++jt)
                acc[it][jt] = __builtin_amdgcn_mfma_f32_16x16x32_bf16(
                    fa[it], fb[jt], acc[it][jt], 0, 0, 0);
    }

    const int row0 = (l >> 4) * 4, col = l & 15;
    #pragma unroll
    for (int it = 0; it < 2; ++it)
        #pragma unroll
        for (int jt = 0; jt < 2; ++jt)
            #pragma unroll
            for (int r = 0; r < 4; ++r) {
                int m = it*16 + row0 + r;
                if (m < 17)
                    Tbuf[((size_t)bh*17 + m)*1024 + n0 + w*32 + jt*16 + col] =
                        acc[it][jt][r];
            }
}

// ---------------------------------------------------------------------------
// M'[bh][p][vd] = sum_d T'[bh][p][d] * WvT[d][h*64+vd]   (p=0..16; p=16->vSum)
// ---------------------------------------------------------------------------
__global__ __launch_bounds__(256) void m_kernel(
    const float* __restrict__ Tbuf, const ushort* __restrict__ WvT,
    float* __restrict__ Mbuf)
{
    __shared__ float Tc[17][132];
    __shared__ float Rd[4][17][64];
    const int bh = blockIdx.x, h = bh & 15;
    const int t = threadIdx.x;
    const int vd = t & 63, stripe = t >> 6;
    float acc[17] = {};
    for (int dc = 0; dc < 1024; dc += 128) {
        __syncthreads();
        for (int i = t; i < 17*128; i += 256) {
            int p = i >> 7, dd = i & 127;
            Tc[p][dd] = Tbuf[((size_t)bh*17 + p)*1024 + dc + dd];
        }
        __syncthreads();
        for (int k = 0; k < 32; ++k) {
            int dd = stripe + 4*k;
            float wv = bf2f(WvT[(size_t)(dc + dd)*1024 + h*64 + vd]);
            #pragma unroll
            for (int p = 0; p < 17; ++p) acc[p] = fmaf(Tc[p][dd], wv, acc[p]);
        }
    }
    __syncthreads();
    #pragma unroll
    for (int p = 0; p < 17; ++p) Rd[stripe][p][vd] = acc[p];
    __syncthreads();
    for (int i = t; i < 17*64; i += 256) {
        int p = i >> 6, v2 = i & 63;
        Mbuf[((size_t)bh*17 + p)*64 + v2] =
            Rd[0][p][v2] + Rd[1][p][v2] + Rd[2][p][v2] + Rd[3][p][v2];
    }
}

// ---------------------------------------------------------------------------
// G'[bh][p][od] = sum_vd M'[bh][p][vd] * WoT[h*64+vd][od]   (p=16 -> g0)
// ---------------------------------------------------------------------------
__global__ __launch_bounds__(256) void g_kernel(
    const float* __restrict__ Mbuf, const ushort* __restrict__ WoT,
    float* __restrict__ Gbuf)
{
    __shared__ float Ms[17][68];
    const int bh = blockIdx.x, h = bh & 15;
    const int t = threadIdx.x;
    for (int i = t; i < 17*64; i += 256)
        Ms[i >> 6][i & 63] = Mbuf[(size_t)bh*17*64 + i];
    __syncthreads();
    for (int oc = 0; oc < 1024; oc += 256) {
        int od = oc + t;
        float acc[17] = {};
        for (int vd = 0; vd < 64; ++vd) {
            float wo = bf2f(WoT[(size_t)(h*64 + vd)*1024 + od]);
            #pragma unroll
            for (int p = 0; p < 17; ++p) acc[p] = fmaf(Ms[p][vd], wo, acc[p]);
        }
        #pragma unroll
        for (int p = 0; p < 17; ++p)
            Gbuf[((size_t)bh*17 + p)*1024 + od] = acc[p];
    }
}

// ---------------------------------------------------------------------------
// A-build: Abuf[b][s][288] bf16: [h*17+p]=qw/z, [h*17+16]=r_h, [272]=[273]=1, rest 0
// ---------------------------------------------------------------------------
__global__ __launch_bounds__(256) void abuild_kernel(
    const float* __restrict__ qwf, const float* __restrict__ kSum,
    ushort* __restrict__ Abuf)
{
    __shared__ float Ks[16][16];
    const int b = blockIdx.x >> 3;
    const int s = (blockIdx.x & 7) * 256 + threadIdx.x;
    const int t = threadIdx.x;
    Ks[t >> 4][t & 15] = kSum[(b*16 + (t >> 4))*16 + (t & 15)];
    __syncthreads();
    ushort* Arow = Abuf + ((size_t)b*2048 + s)*288;
    for (int h = 0; h < 16; ++h) {
        const float* qp = qwf + (((size_t)(b*16 + h))*2048 + s)*16;
        float q[16];
        #pragma unroll
        for (int i = 0; i < 4; ++i)
            *(float4*)(q + i*4) = *(const float4*)(qp + i*4);
        float qwk = 0.f;
        #pragma unroll
        for (int p = 0; p < 16; ++p) qwk = fmaf(q[p], Ks[h][p], qwk);
        float z = 2048.0f + qwk;
        float invz = 1.0f / z;
        float r = -qwk * invz * (1.0f / 2048.0f);
        #pragma unroll
        for (int p = 0; p < 16; ++p) Arow[h*17 + p] = f2bf(q[p] * invz);
        Arow[h*17 + 16] = f2bf(r);
    }
    Arow[272] = 0x3F80;
    Arow[273] = 0x3F80;
    #pragma unroll
    for (int k = 274; k < 288; ++k) Arow[k] = 0;
}

// ---------------------------------------------------------------------------
// B-build: Bbuf[b][od][288] bf16: [h*17+p]=G', [272/273]=base hi/lo, rest 0
// base[b][od] = sum_h G'[bh][16][od] / 2048
// ---------------------------------------------------------------------------
__global__ __launch_bounds__(256) void bbuild_kernel(
    const float* __restrict__ Gbuf, ushort* __restrict__ Bbuf)
{
    const int b = blockIdx.x >> 2;
    const int od = (blockIdx.x & 3) * 256 + threadIdx.x;
    ushort* row = Bbuf + ((size_t)b*1024 + od)*288;
    float base = 0.f;
    for (int h = 0; h < 16; ++h) {
        size_t gb = (size_t)(b*16 + h) * 17;
        #pragma unroll
        for (int p = 0; p < 17; ++p) {
            float g = Gbuf[(gb + p)*1024 + od];
            row[h*17 + p] = f2bf(g);
            if (p == 16) base += g;
        }
    }
    base *= (1.0f / 2048.0f);
    ushort hi = f2bf(base);
    row[272] = hi;
    row[273] = f2bf(base - bf2f(hi));
    #pragma unroll
    for (int k = 274; k < 288; ++k) row[k] = 0;
}

// ---------------------------------------------------------------------------
extern "C" void kernel_launch(void* const* d_in, const int* in_sizes, int n_in,
                              void* d_out, int out_size, void* d_ws, size_t ws_size,
                              hipStream_t stream)
{
    const float* x       = (const float*)d_in[0];
    const float* qkv_w   = (const float*)d_in[1];
    const float* out_w   = (const float*)d_in[2];
    const float* centers = (const float*)d_in[3];
    const float* lscales = (const float*)d_in[4];
    const float* amps    = (const float*)d_in[5];
    float* out  = (float*)d_out;                      // [B,S,D]
    float* traj = out + (size_t)NB*SEQ*DIM;           // [B,S,D]

    char* wsb = (char*)d_ws;
    ushort* xh   = (ushort*)(wsb);                    // [0,8) MB
    ushort* wqk  = (ushort*)(wsb + (8u<<20));         // [8,12) MB
    ushort* xT   = (ushort*)(wsb + (12u<<20));        // [12,20) MB
    ushort* qbuf = (ushort*)(wsb + (20u<<20));        // [20,28) MB
    ushort* kbuf = (ushort*)(wsb + (28u<<20));        // [28,36) MB
    // aliases (dead regions reused):
    float*  qwf  = (float*)(wsb);                     // [0,4) after qkgemm
    ushort* kwA  = (ushort*)(wsb + (4u<<20));         // [4,8)
    ushort* WvT  = (ushort*)(wsb + (8u<<20));         // [8,10) after qkgemm
    ushort* WoT  = (ushort*)(wsb + (10u<<20));        // [10,12)
    float*  Tbuf = (float*)(wsb + (20u<<20));         // [20,22.3) after splat_q
    float*  Mbuf = (float*)(wsb + (23u<<20));
    float*  Gbuf = (float*)(wsb + (24u<<20));
    ushort* Abuf = (ushort*)(wsb + (28u<<20));        // [28,30.3) after splat_k
    ushort* Bbuf = (ushort*)(wsb + (31u<<20));
    float*  kSum = (float*)(wsb + (36u<<20));
    float*  sbuf = (float*)(wsb + (40u<<20));
    float*  invb = sbuf + 4096;

    cvt_hi_kernel<<<4096, 256, 0, stream>>>(x, xh, 4194304);
    cvt_hi_kernel<<<2048, 256, 0, stream>>>(qkv_w, wqk, 2097152);
    txp_kernel<<<dim3(16, 32), 256, 0, stream>>>(x, xT, 2048, 1024);
    txp_kernel<<<dim3(16, 32), 256, 0, stream>>>(x + 2097152, xT + 2097152, 2048, 1024);
    traj_stats_kernel<<<1024, 256, 0, stream>>>(x, sbuf, invb);
    traj_kernel<<<NB*SEQ, 256, 0, stream>>>(x, sbuf, invb, traj);
    // q,k projection -> head-major bf16
    mm_kernel<1024,3><<<dim3(16, 32, 1), 256, 0, stream>>>(
        xh, wqk, nullptr, qbuf, kbuf, 0, 0);
    txp_kernel<<<dim3(16, 16), 256, 0, stream>>>(qkv_w + 2097152, WvT, 1024, 1024);
    txp_kernel<<<dim3(16, 16), 256, 0, stream>>>(out_w, WoT, 1024, 1024);
    splat_q_kernel<<<256, 256, 0, stream>>>(qbuf, qwf, centers, lscales, amps);
    splat_k_kernel<<<256, 256, 0, stream>>>(kbuf, kwA, centers, lscales, amps);
    ksum_kernel<<<32, 256, 0, stream>>>(kwA, kSum);
    tgemm_kernel<<<dim3(8, 32), 256, 0, stream>>>(kwA, xT, Tbuf);
    m_kernel<<<32, 256, 0, stream>>>(Tbuf, WvT, Mbuf);
    g_kernel<<<32, 256, 0, stream>>>(Mbuf, WoT, Gbuf);
    abuild_kernel<<<16, 256, 0, stream>>>(qwf, kSum, Abuf);
    bbuild_kernel<<<8, 256, 0, stream>>>(Gbuf, Bbuf);
    // out[b] = Abuf[b] @ Bbuf[b]^T  (K=288, base folded in slots 272/273)
    mm_kernel<288,4><<<dim3(8, 16, 2), 256, 0, stream>>>(
        Abuf, Bbuf, out, nullptr, nullptr, 2048L*288, 1024L*288);
}

// Round 7
// 307.062 us; speedup vs baseline: 1.4048x; 1.4048x over previous
//
#include <hip/hip_runtime.h>
#include <math.h>

// Problem constants (B=2, S=2048, D=1024, H=16, hd=64, K=16)
#define SEQ 2048
#define DIM 1024
#define NB  2
#define NH  16

typedef __attribute__((ext_vector_type(8))) short short8;
typedef __attribute__((ext_vector_type(4))) float floatx4;

__device__ __forceinline__ ushort f2bf(float f) {
    unsigned u = __float_as_uint(f);
    return (ushort)((u + 0x7FFFu + ((u >> 16) & 1u)) >> 16);
}
__device__ __forceinline__ float bf2f(ushort h) {
    return __uint_as_float(((unsigned)h) << 16);
}
// async global->LDS, 16B per lane; LDS dest = wave-uniform base + lane*16
__device__ __forceinline__ void gload16(const void* g, char* lds_base) {
    __builtin_amdgcn_global_load_lds(
        (const __attribute__((address_space(1))) void*)g,
        (__attribute__((address_space(3))) void*)lds_base, 16, 0, 0);
}

// ---------------------------------------------------------------------------
// fp32 -> bf16
// ---------------------------------------------------------------------------
__global__ __launch_bounds__(256) void cvt_hi_kernel(
    const float* __restrict__ src, ushort* __restrict__ dst, int n)
{
    int i = (blockIdx.x * 256 + threadIdx.x) * 4;
    if (i >= n) return;
    float4 v = *(const float4*)(src + i);
    ushort4 o;
    o.x = f2bf(v.x); o.y = f2bf(v.y); o.z = f2bf(v.z); o.w = f2bf(v.w);
    *(ushort4*)(dst + i) = o;
}

// ---------------------------------------------------------------------------
// transpose + cvt: src [R][C] fp32 -> dst [C][R] bf16. grid (C/64, R/64).
// ---------------------------------------------------------------------------
__global__ __launch_bounds__(256) void txp_kernel(
    const float* __restrict__ src, ushort* __restrict__ dst, int R, int C)
{
    __shared__ ushort T[64 * 72];
    const int t = threadIdx.x;
    const int c0 = blockIdx.x * 64, r0 = blockIdx.y * 64;
    #pragma unroll
    for (int it = 0; it < 4; ++it) {
        int r = 16 * it + (t >> 4);
        int c4 = (t & 15) * 4;
        float4 v = *(const float4*)(src + (size_t)(r0 + r) * C + c0 + c4);
        T[(c4 + 0) * 72 + r] = f2bf(v.x);
        T[(c4 + 1) * 72 + r] = f2bf(v.y);
        T[(c4 + 2) * 72 + r] = f2bf(v.z);
        T[(c4 + 3) * 72 + r] = f2bf(v.w);
    }
    __syncthreads();
    {
        int c = t >> 2, rb = (t & 3) * 16;
        ushort tmp[16];
        #pragma unroll
        for (int i = 0; i < 16; ++i) tmp[i] = T[c * 72 + rb + i];
        ushort* d = dst + (size_t)(c0 + c) * R + r0 + rb;
        *(short8*)(d) = *(short8*)(tmp);
        *(short8*)(d + 8) = *(short8*)(tmp + 8);
    }
}

// ---------------------------------------------------------------------------
// K1: per-diff stats
// ---------------------------------------------------------------------------
__global__ __launch_bounds__(256) void traj_stats_kernel(
    const float* __restrict__ x, float* __restrict__ sbuf, float* __restrict__ invbuf)
{
    const int wave = threadIdx.x >> 6;
    const int lane = threadIdx.x & 63;
    const int row  = blockIdx.x * 4 + wave;
    const int NR = NB * (SEQ - 1);
    if (row >= NR) return;
    const int b = row / (SEQ - 1);
    const int j = row - b * (SEQ - 1);
    const float* x0 = x + ((size_t)(b * SEQ + j)) * DIM;
    const float* x1 = x0 + DIM;
    float sum = 0.f;
    #pragma unroll
    for (int q = 0; q < 4; ++q) {
        int idx = q * 256 + lane * 4;
        float4 a = *(const float4*)(x0 + idx);
        float4 c = *(const float4*)(x1 + idx);
        float dx = c.x-a.x, dy = c.y-a.y, dz = c.z-a.z, dw = c.w-a.w;
        sum += dx*dx + dy*dy + dz*dz + dw*dw;
    }
    #pragma unroll
    for (int off = 32; off > 0; off >>= 1) sum += __shfl_down(sum, off);
    if (lane == 0) {
        float mag = sqrtf(sum);
        sbuf[row]   = tanhf(mag);
        invbuf[row] = 1.0f / fmaxf(mag, 1e-8f);
    }
}

// ---------------------------------------------------------------------------
// K2: traj combine (window <= 8)
// ---------------------------------------------------------------------------
__global__ __launch_bounds__(256) void traj_kernel(
    const float* __restrict__ x, const float* __restrict__ sbuf,
    const float* __restrict__ invbuf, float* __restrict__ traj_out)
{
    const int bp = blockIdx.x;
    const int b  = bp >> 11;
    const int p  = bp & (SEQ - 1);
    int ws = p - 8; if (ws < 0) ws = 0;
    const int wlen = p - ws;
    const float wsz = (float)((p - ws) > 1 ? (p - ws) : 1);
    const int base = b * (SEQ - 1) + ws;

    float Z = 0.f;
    for (int t = 0; t < wlen; ++t)
        Z += sbuf[base + t] * ((float)(t + 1) / wsz);
    const float scale = 1.0f / fmaxf(Z, 1e-8f);

    const int d0 = threadIdx.x * 4;
    const float* xb = x + ((size_t)(b * SEQ + ws)) * DIM + d0;
    float4 prev = *(const float4*)xb;
    float4 acc = make_float4(0.f,0.f,0.f,0.f);
    for (int t = 0; t < wlen; ++t) {
        xb += DIM;
        float4 cur = *(const float4*)xb;
        float cc = sbuf[base + t] * ((float)(t + 1) / wsz) * invbuf[base + t] * scale;
        acc.x += cc * (cur.x - prev.x);
        acc.y += cc * (cur.y - prev.y);
        acc.z += cc * (cur.z - prev.z);
        acc.w += cc * (cur.w - prev.w);
        prev = cur;
    }
    *(float4*)(traj_out + (size_t)bp * DIM + d0) = acc;
}

// ---------------------------------------------------------------------------
// MFMA bf16 GEMM, m97 structure: C[M,N] = A[M,KTOT] @ B[N,KTOT]^T.
// EPI=3 (q/k): bf16 head-major store: n<1024 -> qwb, else kwb.
// EPI=4: fp32 store to cout[(z*2048+gm)*1024+gn] (final K=288 gemm).
// ---------------------------------------------------------------------------
template<int KTOT, int EPI>
__global__ __launch_bounds__(256) void mm_kernel(
    const ushort* __restrict__ Ag, const ushort* __restrict__ Bg,
    float* __restrict__ cout, ushort* __restrict__ qwb, ushort* __restrict__ kwb,
    long aStride, long bStride)
{
    __shared__ char smem[16384];
    const int tid = threadIdx.x;
    const int l = tid & 63;
    const int w = tid >> 6;
    const int wm = w >> 1, wn = w & 1;
    const int n0 = blockIdx.x * 128;
    const int m0 = blockIdx.y * 128;
    const int zb = blockIdx.z;

    char* a_s = smem;
    char* b_s = smem + 8192;

    const int srow = 32 * w + (l >> 2);
    const int scol = (l & 3) * 8;
    const ushort* Ah = Ag + (size_t)zb * aStride + (size_t)(m0 + srow) * KTOT + scol;
    const ushort* Bh = Bg + (size_t)zb * bStride + (size_t)(n0 + srow) * KTOT + scol;

    floatx4 acc[4][4] = {};
    const int fr = l & 15;
    const int fq = (l >> 4) * 16;

    for (int kb = 0; kb < KTOT; kb += 32) {
        if (kb) __syncthreads();
        gload16(Ah + kb,            a_s + w*2048);
        gload16(Ah + kb + 16*KTOT,  a_s + w*2048 + 1024);
        gload16(Bh + kb,            b_s + w*2048);
        gload16(Bh + kb + 16*KTOT,  b_s + w*2048 + 1024);
        __syncthreads();
        short8 fa[4], fb[4];
        #pragma unroll
        for (int t = 0; t < 4; ++t) {
            fa[t] = *(const short8*)(a_s + ((wm*64 + t*16 + fr) << 6) + fq);
            fb[t] = *(const short8*)(b_s + ((wn*64 + t*16 + fr) << 6) + fq);
        }
        #pragma unroll
        for (int it = 0; it < 4; ++it)
            #pragma unroll
            for (int jt = 0; jt < 4; ++jt)
                acc[it][jt] = __builtin_amdgcn_mfma_f32_16x16x32_bf16(
                    fa[it], fb[jt], acc[it][jt], 0, 0, 0);
    }

    const int row0 = (l >> 4) * 4;   // C: row=(l>>4)*4+reg, col=l&15
    const int col  = l & 15;

    if (EPI == 3) {
        ushort* obuf = (n0 < 1024) ? qwb : kwb;
        const int nb = n0 & 1023;
        #pragma unroll
        for (int it = 0; it < 4; ++it)
            #pragma unroll
            for (int jt = 0; jt < 4; ++jt)
                #pragma unroll
                for (int r = 0; r < 4; ++r) {
                    int gm = m0 + wm*64 + it*16 + row0 + r;     // token
                    int gn = nb + wn*64 + jt*16 + col;          // h*64+d
                    int hh = gn >> 6, d = gn & 63;
                    int bb = gm >> 11, ss = gm & (SEQ - 1);
                    obuf[(((size_t)(bb*NH + hh))*SEQ + ss)*64 + d] = f2bf(acc[it][jt][r]);
                }
    } else {
        #pragma unroll
        for (int it = 0; it < 4; ++it)
            #pragma unroll
            for (int jt = 0; jt < 4; ++jt)
                #pragma unroll
                for (int r = 0; r < 4; ++r) {
                    int gm = m0 + wm*64 + it*16 + row0 + r;
                    int gn = n0 + wn*64 + jt*16 + col;
                    cout[((size_t)(zb*2048 + gm))*1024 + gn] = acc[it][jt][r];
                }
    }
}

// ---------------------------------------------------------------------------
// Splat weights (q side): fp32 out [bh][s][16]
// ---------------------------------------------------------------------------
__global__ __launch_bounds__(256) void splat_q_kernel(
    const ushort* __restrict__ qk, float* __restrict__ wout,
    const float* __restrict__ centers, const float* __restrict__ lscales,
    const float* __restrict__ amps)
{
    __shared__ float Cs[16*64];
    __shared__ float Pr[48];
    const int tid = threadIdx.x;
    const int bh  = blockIdx.x >> 3;
    const int h   = bh & 15;
    const int s   = (blockIdx.x & 7) * 256 + tid;
    *(float4*)(Cs + tid*4) = *(const float4*)(centers + (size_t)h*1024 + tid*4);
    if (tid < 16) {
        float s2 = __expf(2.f * lscales[h*16 + tid]);
        Pr[tid]      = -0.5f / s2;
        Pr[16 + tid] = 1.f / (1.f + __expf(-amps[h*16 + tid]));
        const float* cp = centers + ((size_t)h*16 + tid)*64;
        float cn = 0.f;
        for (int i = 0; i < 64; ++i) cn += cp[i]*cp[i];
        Pr[32 + tid] = cn;
    }
    __syncthreads();

    float q[64];
    const ushort* qp = qk + ((size_t)bh*SEQ + s)*64;
    #pragma unroll
    for (int i = 0; i < 8; ++i) {
        short8 v = *(const short8*)(qp + i*8);
        #pragma unroll
        for (int j = 0; j < 8; ++j) q[i*8+j] = bf2f((ushort)v[j]);
    }
    float tn = 0.f;
    #pragma unroll
    for (int i = 0; i < 64; ++i) tn = fmaf(q[i], q[i], tn);

    float o16[16];
    #pragma unroll 4
    for (int sp = 0; sp < 16; ++sp) {
        const float* cp = Cs + sp*64;
        float cr = 0.f;
        #pragma unroll
        for (int i = 0; i < 64; ++i) cr = fmaf(q[i], cp[i], cr);
        float dq = tn - 2.f*cr + Pr[32 + sp];
        o16[sp] = __expf(dq * Pr[sp]) * Pr[16 + sp];
    }
    float* op = wout + ((size_t)bh*SEQ + s)*16;
    #pragma unroll
    for (int i = 0; i < 4; ++i)
        *(float4*)(op + i*4) = *(float4*)(o16 + i*4);
}

// ---------------------------------------------------------------------------
// Splat weights (k side): transposed bf16 out kwA [bh][32 rows][2048]:
// rows 0..15 = kw^T, row 16 = ones, rows 17..31 unused.
// ---------------------------------------------------------------------------
__global__ __launch_bounds__(256) void splat_k_kernel(
    const ushort* __restrict__ qk, ushort* __restrict__ kwA,
    const float* __restrict__ centers, const float* __restrict__ lscales,
    const float* __restrict__ amps)
{
    __shared__ float Cs[16*64];
    __shared__ float Pr[48];
    __shared__ ushort Tr[16][264];
    const int tid = threadIdx.x;
    const int bh  = blockIdx.x >> 3;
    const int h   = bh & 15;
    const int s0  = (blockIdx.x & 7) * 256;
    const int s   = s0 + tid;
    *(float4*)(Cs + tid*4) = *(const float4*)(centers + (size_t)h*1024 + tid*4);
    if (tid < 16) {
        float s2 = __expf(2.f * lscales[h*16 + tid]);
        Pr[tid]      = -0.5f / s2;
        Pr[16 + tid] = 1.f / (1.f + __expf(-amps[h*16 + tid]));
        const float* cp = centers + ((size_t)h*16 + tid)*64;
        float cn = 0.f;
        for (int i = 0; i < 64; ++i) cn += cp[i]*cp[i];
        Pr[32 + tid] = cn;
    }
    __syncthreads();

    float q[64];
    const ushort* qp = qk + ((size_t)bh*SEQ + s)*64;
    #pragma unroll
    for (int i = 0; i < 8; ++i) {
        short8 v = *(const short8*)(qp + i*8);
        #pragma unroll
        for (int j = 0; j < 8; ++j) q[i*8+j] = bf2f((ushort)v[j]);
    }
    float tn = 0.f;
    #pragma unroll
    for (int i = 0; i < 64; ++i) tn = fmaf(q[i], q[i], tn);

    #pragma unroll 4
    for (int sp = 0; sp < 16; ++sp) {
        const float* cp = Cs + sp*64;
        float cr = 0.f;
        #pragma unroll
        for (int i = 0; i < 64; ++i) cr = fmaf(q[i], cp[i], cr);
        float dq = tn - 2.f*cr + Pr[32 + sp];
        Tr[sp][tid] = f2bf(__expf(dq * Pr[sp]) * Pr[16 + sp]);
    }
    __syncthreads();
    {
        int p = tid >> 4, seg = (tid & 15) * 16;
        ushort tmp[16];
        #pragma unroll
        for (int i = 0; i < 16; ++i) tmp[i] = Tr[p][seg + i];
        ushort* d = kwA + ((size_t)bh*32 + p)*2048 + s0 + seg;
        *(short8*)(d) = *(short8*)(tmp);
        *(short8*)(d + 8) = *(short8*)(tmp + 8);
    }
    kwA[((size_t)bh*32 + 16)*2048 + s] = 0x3F80;   // ones row
}

// ---------------------------------------------------------------------------
// kSum[bh][p] = sum_s kwA[bh][p][s]
// ---------------------------------------------------------------------------
__global__ __launch_bounds__(256) void ksum_kernel(
    const ushort* __restrict__ kwA, float* __restrict__ kSum)
{
    __shared__ float R[256];
    const int bh = blockIdx.x;
    const int t = threadIdx.x;
    const int p = t >> 4, seg = t & 15;
    const ushort* row = kwA + ((size_t)bh*32 + p)*2048 + seg*128;
    float s = 0.f;
    #pragma unroll
    for (int i = 0; i < 16; ++i) {
        short8 v = *(const short8*)(row + i*8);
        #pragma unroll
        for (int j = 0; j < 8; ++j) s += bf2f((ushort)v[j]);
    }
    R[t] = s;
    __syncthreads();
    if (t < 16) {
        float tot = 0.f;
        #pragma unroll
        for (int j = 0; j < 16; ++j) tot += R[t*16 + j];
        kSum[bh*16 + t] = tot;
    }
}

// ---------------------------------------------------------------------------
// T' [bh][17][1024] = kwA[bh] (32x2048) @ xT[b] (1024x2048)^T, rows<17 stored.
// ---------------------------------------------------------------------------
__global__ __launch_bounds__(256) void tgemm_kernel(
    const ushort* __restrict__ kwA, const ushort* __restrict__ xT,
    float* __restrict__ Tbuf)
{
    __shared__ char smem[2048 + 8192];
    const int tid = threadIdx.x;
    const int l = tid & 63, w = tid >> 6;
    const int bh = blockIdx.y, b = bh >> 4;
    const int n0 = blockIdx.x * 128;
    const ushort* Ab = kwA + (size_t)bh * 32 * 2048;
    const ushort* Bb = xT + ((size_t)b * 1024 + n0) * 2048;
    char* a_s = smem;
    char* b_s = smem + 2048;
    const int lr = l >> 2, lc = (l & 3) * 8;
    floatx4 acc[2][2] = {};
    const int fr = l & 15, fq = (l >> 4) * 16;

    for (int kb = 0; kb < 2048; kb += 32) {
        if (kb) __syncthreads();
        if (w < 2)
            gload16(Ab + (size_t)(16*w + lr)*2048 + kb + lc, a_s + w*1024);
        gload16(Bb + (size_t)(32*w + lr)*2048 + kb + lc,      b_s + w*2048);
        gload16(Bb + (size_t)(32*w + 16 + lr)*2048 + kb + lc, b_s + w*2048 + 1024);
        __syncthreads();
        short8 fa[2], fb[2];
        #pragma unroll
        for (int i = 0; i < 2; ++i) {
            fa[i] = *(const short8*)(a_s + ((i*16 + fr) << 6) + fq);
            fb[i] = *(const short8*)(b_s + ((w*32 + i*16 + fr) << 6) + fq);
        }
        #pragma unroll
        for (int it = 0; it < 2; ++it)
            #pragma unroll
            for (int jt = 0; jt < 2; ++jt)
                acc[it][jt] = __builtin_amdgcn_mfma_f32_16x16x32_bf16(
                    fa[it], fb[jt], acc[it][jt], 0, 0, 0);
    }

    const int row0 = (l >> 4) * 4, col = l & 15;
    #pragma unroll
    for (int it = 0; it < 2; ++it)
        #pragma unroll
        for (int jt = 0; jt < 2; ++jt)
            #pragma unroll
            for (int r = 0; r < 4; ++r) {
                int m = it*16 + row0 + r;
                if (m < 17)
                    Tbuf[((size_t)bh*17 + m)*1024 + n0 + w*32 + jt*16 + col] =
                        acc[it][jt][r];
            }
}

// ---------------------------------------------------------------------------
// Fused M+G: one block per bh.
//   M[32][64] = Ts[32][1024] @ Wv_h[64][1024]^T   (Ts rows 17.. = 0)
//   G[17][1024] = M @ Wo_h[1024][64]^T            (Wo_h = Wob cols h*64..)
// MFMA 16x16x32; Ts/Ms padded for conflict-free frag reads; Wv/Wo staged
// with register prefetch to hide global latency.
// ---------------------------------------------------------------------------
__global__ __launch_bounds__(256) void mg_kernel(
    const float* __restrict__ Tbuf, const ushort* __restrict__ Wvb,
    const ushort* __restrict__ Wob, float* __restrict__ Gbuf)
{
    __shared__ ushort Ts[32*1032];      // rows padded: stride 516 dwords (2-way free)
    __shared__ ushort Ms[32*72];
    __shared__ ushort Bv[64*132];       // phase-1 BK=128 chunk, stride 66 dwords
    __shared__ ushort Bo[4][16*72];     // phase-2 per-wave tiles
    const int tid = threadIdx.x;
    const int l = tid & 63;
    const int w = tid >> 6;
    const int bh = blockIdx.x;
    const int h = bh & 15;
    const int qrow = l & 15, quad = l >> 4;

    const ushort* WvH = Wvb + (size_t)h*64*1024;

    // prefetch first Wv chunk (overlaps phase 0)
    short8 pre[4];
    {
        int row = tid >> 2;
        #pragma unroll
        for (int i2 = 0; i2 < 4; ++i2)
            pre[i2] = *(const short8*)(WvH + (size_t)row*1024 + ((tid&3) + 4*i2)*8);
    }

    // phase 0: T' fp32 -> bf16 into Ts; rows 17..31 zeroed
    for (int i = tid*4; i < 32*1024; i += 1024) {
        int row = i >> 10, col = i & 1023;
        ushort4 o;
        if (row < 17) {
            float4 v = *(const float4*)(Tbuf + ((size_t)bh*17 + row)*1024 + col);
            o.x = f2bf(v.x); o.y = f2bf(v.y); o.z = f2bf(v.z); o.w = f2bf(v.w);
        } else { o.x = 0; o.y = 0; o.z = 0; o.w = 0; }
        *(ushort4*)(Ts + (size_t)row*1032 + col) = o;
    }
    __syncthreads();

    // phase 1: wave w owns vd-tile w. BK=128, reg-prefetch staging.
    floatx4 accM[2] = {};
    for (int kb = 0; kb < 1024; kb += 128) {
        {
            int row = tid >> 2;
            #pragma unroll
            for (int i2 = 0; i2 < 4; ++i2)
                *(short8*)(Bv + row*132 + ((tid&3) + 4*i2)*8) = pre[i2];
        }
        __syncthreads();
        if (kb + 128 < 1024) {
            int row = tid >> 2;
            #pragma unroll
            for (int i2 = 0; i2 < 4; ++i2)
                pre[i2] = *(const short8*)(WvH + (size_t)row*1024 + kb + 128 + ((tid&3) + 4*i2)*8);
        }
        #pragma unroll
        for (int ks = 0; ks < 4; ++ks) {
            short8 fb = *(const short8*)(Bv + (w*16 + qrow)*132 + ks*32 + quad*8);
            #pragma unroll
            for (int mt = 0; mt < 2; ++mt) {
                short8 fa = *(const short8*)(Ts + (size_t)(mt*16 + qrow)*1032 + kb + ks*32 + quad*8);
                accM[mt] = __builtin_amdgcn_mfma_f32_16x16x32_bf16(fa, fb, accM[mt], 0, 0, 0);
            }
        }
        __syncthreads();
    }
    // C[m=p][n=vd]: p = mt*16 + quad*4 + r, vd = w*16 + qrow
    #pragma unroll
    for (int mt = 0; mt < 2; ++mt)
        #pragma unroll
        for (int r = 0; r < 4; ++r)
            Ms[(mt*16 + quad*4 + r)*72 + w*16 + qrow] = f2bf(accM[mt][r]);
    __syncthreads();

    // phase 2: wave w handles od-tiles nt = 4*t2 + w. A-frags hoisted.
    short8 fa2[2][2];
    #pragma unroll
    for (int mt = 0; mt < 2; ++mt)
        #pragma unroll
        for (int ks = 0; ks < 2; ++ks)
            fa2[mt][ks] = *(const short8*)(Ms + (mt*16 + qrow)*72 + ks*32 + quad*8);

    short8 pv0, pv1;
    {
        const ushort* p = Wob + (size_t)((4*0 + w)*16 + qrow)*1024 + h*64;
        pv0 = *(const short8*)(p + quad*8);
        pv1 = *(const short8*)(p + (quad+4)*8);
    }
    for (int t2 = 0; t2 < 16; ++t2) {
        const int od0 = (4*t2 + w) * 16;
        *(short8*)(Bo[w] + qrow*72 + quad*8)     = pv0;
        *(short8*)(Bo[w] + qrow*72 + (quad+4)*8) = pv1;
        __syncthreads();
        if (t2 < 15) {
            const ushort* p = Wob + (size_t)((4*(t2+1) + w)*16 + qrow)*1024 + h*64;
            pv0 = *(const short8*)(p + quad*8);
            pv1 = *(const short8*)(p + (quad+4)*8);
        }
        floatx4 acc2[2] = {};
        #pragma unroll
        for (int ks = 0; ks < 2; ++ks) {
            short8 fb = *(const short8*)(Bo[w] + qrow*72 + ks*32 + quad*8);
            #pragma unroll
            for (int mt = 0; mt < 2; ++mt)
                acc2[mt] = __builtin_amdgcn_mfma_f32_16x16x32_bf16(fa2[mt][ks], fb, acc2[mt], 0, 0, 0);
        }
        #pragma unroll
        for (int r = 0; r < 4; ++r)
            Gbuf[((size_t)bh*17 + quad*4 + r)*1024 + od0 + qrow] = acc2[0][r];
        if (quad == 0)
            Gbuf[((size_t)bh*17 + 16)*1024 + od0 + qrow] = acc2[1][0];
        __syncthreads();
    }
}

// ---------------------------------------------------------------------------
// A-build: Abuf[b][s][288] bf16
// ---------------------------------------------------------------------------
__global__ __launch_bounds__(256) void abuild_kernel(
    const float* __restrict__ qwf, const float* __restrict__ kSum,
    ushort* __restrict__ Abuf)
{
    __shared__ float Ks[16][16];
    const int b = blockIdx.x >> 3;
    const int s = (blockIdx.x & 7) * 256 + threadIdx.x;
    const int t = threadIdx.x;
    Ks[t >> 4][t & 15] = kSum[(b*16 + (t >> 4))*16 + (t & 15)];
    __syncthreads();
    ushort* Arow = Abuf + ((size_t)b*2048 + s)*288;
    for (int h = 0; h < 16; ++h) {
        const float* qp = qwf + (((size_t)(b*16 + h))*2048 + s)*16;
        float q[16];
        #pragma unroll
        for (int i = 0; i < 4; ++i)
            *(float4*)(q + i*4) = *(const float4*)(qp + i*4);
        float qwk = 0.f;
        #pragma unroll
        for (int p = 0; p < 16; ++p) qwk = fmaf(q[p], Ks[h][p], qwk);
        float z = 2048.0f + qwk;
        float invz = 1.0f / z;
        float r = -qwk * invz * (1.0f / 2048.0f);
        #pragma unroll
        for (int p = 0; p < 16; ++p) Arow[h*17 + p] = f2bf(q[p] * invz);
        Arow[h*17 + 16] = f2bf(r);
    }
    Arow[272] = 0x3F80;
    Arow[273] = 0x3F80;
    #pragma unroll
    for (int k = 274; k < 288; ++k) Arow[k] = 0;
}

// ---------------------------------------------------------------------------
// B-build: Bbuf[b][od][288] bf16
// ---------------------------------------------------------------------------
__global__ __launch_bounds__(256) void bbuild_kernel(
    const float* __restrict__ Gbuf, ushort* __restrict__ Bbuf)
{
    const int b = blockIdx.x >> 2;
    const int od = (blockIdx.x & 3) * 256 + threadIdx.x;
    ushort* row = Bbuf + ((size_t)b*1024 + od)*288;
    float base = 0.f;
    for (int h = 0; h < 16; ++h) {
        size_t gb = (size_t)(b*16 + h) * 17;
        #pragma unroll
        for (int p = 0; p < 17; ++p) {
            float g = Gbuf[(gb + p)*1024 + od];
            row[h*17 + p] = f2bf(g);
            if (p == 16) base += g;
        }
    }
    base *= (1.0f / 2048.0f);
    ushort hi = f2bf(base);
    row[272] = hi;
    row[273] = f2bf(base - bf2f(hi));
    #pragma unroll
    for (int k = 274; k < 288; ++k) row[k] = 0;
}

// ---------------------------------------------------------------------------
extern "C" void kernel_launch(void* const* d_in, const int* in_sizes, int n_in,
                              void* d_out, int out_size, void* d_ws, size_t ws_size,
                              hipStream_t stream)
{
    const float* x       = (const float*)d_in[0];
    const float* qkv_w   = (const float*)d_in[1];
    const float* out_w   = (const float*)d_in[2];
    const float* centers = (const float*)d_in[3];
    const float* lscales = (const float*)d_in[4];
    const float* amps    = (const float*)d_in[5];
    float* out  = (float*)d_out;                      // [B,S,D]
    float* traj = out + (size_t)NB*SEQ*DIM;           // [B,S,D]

    char* wsb = (char*)d_ws;
    ushort* xh   = (ushort*)(wsb);                    // [0,8) MB
    ushort* wqk  = (ushort*)(wsb + (8u<<20));         // [8,12) MB (q,k weights)
    ushort* xT   = (ushort*)(wsb + (12u<<20));        // [12,20) MB
    ushort* qbuf = (ushort*)(wsb + (20u<<20));        // [20,28) MB
    ushort* kbuf = (ushort*)(wsb + (28u<<20));        // [28,36) MB
    // aliases (dead regions reused):
    float*  qwf  = (float*)(wsb);                     // [0,4) after qkgemm
    ushort* kwA  = (ushort*)(wsb + (4u<<20));         // [4,8)
    ushort* Wvb  = (ushort*)(wsb + (8u<<20));         // [8,10) after qkgemm
    ushort* Wob  = (ushort*)(wsb + (10u<<20));        // [10,12)
    float*  Tbuf = (float*)(wsb + (20u<<20));         // [20,22.3) after splat_q
    float*  Gbuf = (float*)(wsb + (24u<<20));         // [24,26.3)
    ushort* Abuf = (ushort*)(wsb + (28u<<20));        // [28,30.3) after splat_k
    ushort* Bbuf = (ushort*)(wsb + (31u<<20));
    float*  kSum = (float*)(wsb + (36u<<20));
    float*  sbuf = (float*)(wsb + (40u<<20));
    float*  invb = sbuf + 4096;

    cvt_hi_kernel<<<4096, 256, 0, stream>>>(x, xh, 4194304);
    cvt_hi_kernel<<<2048, 256, 0, stream>>>(qkv_w, wqk, 2097152);
    txp_kernel<<<dim3(16, 32), 256, 0, stream>>>(x, xT, 2048, 1024);
    txp_kernel<<<dim3(16, 32), 256, 0, stream>>>(x + 2097152, xT + 2097152, 2048, 1024);
    traj_stats_kernel<<<1024, 256, 0, stream>>>(x, sbuf, invb);
    traj_kernel<<<NB*SEQ, 256, 0, stream>>>(x, sbuf, invb, traj);
    // q,k projection -> head-major bf16
    mm_kernel<1024,3><<<dim3(16, 32, 1), 256, 0, stream>>>(
        xh, wqk, nullptr, qbuf, kbuf, 0, 0);
    // v/out weights, bf16 row-major (overwrite wqk after qk gemm)
    cvt_hi_kernel<<<1024, 256, 0, stream>>>(qkv_w + 2097152, Wvb, 1048576);
    cvt_hi_kernel<<<1024, 256, 0, stream>>>(out_w, Wob, 1048576);
    splat_q_kernel<<<256, 256, 0, stream>>>(qbuf, qwf, centers, lscales, amps);
    splat_k_kernel<<<256, 256, 0, stream>>>(kbuf, kwA, centers, lscales, amps);
    ksum_kernel<<<32, 256, 0, stream>>>(kwA, kSum);
    tgemm_kernel<<<dim3(8, 32), 256, 0, stream>>>(kwA, xT, Tbuf);
    mg_kernel<<<32, 256, 0, stream>>>(Tbuf, Wvb, Wob, Gbuf);
    abuild_kernel<<<16, 256, 0, stream>>>(qwf, kSum, Abuf);
    bbuild_kernel<<<8, 256, 0, stream>>>(Gbuf, Bbuf);
    // out[b] = Abuf[b] @ Bbuf[b]^T  (K=288)
    mm_kernel<288,4><<<dim3(8, 16, 2), 256, 0, stream>>>(
        Abuf, Bbuf, out, nullptr, nullptr, 2048L*288, 1024L*288);
}